// Round 9
// baseline (147.958 us; speedup 1.0000x reference)
//
#include <hip/hip_runtime.h>
#include <math.h>

#define Bn 4
#define Cn 64
#define On 64
#define Hn 128
#define Wn 128
#define HWn (Hn * Wn)

typedef __attribute__((ext_vector_type(8))) short s16x8;
typedef __attribute__((ext_vector_type(4))) float f32x4;

__device__ __forceinline__ unsigned short f2bf(float f) {
    unsigned u = __float_as_uint(f);
    u += 0x7fffu + ((u >> 16) & 1u);  // RTNE (finite values)
    return (unsigned short)(u >> 16);
}
__device__ __forceinline__ float bf2f(unsigned short u) {
    return __uint_as_float(((unsigned)u) << 16);
}
// 64-B LDS rows (32 ushorts): chunk swizzle -> exact 2-way (free) banks.
// swz(row, ch) is a USHORT index; one row occupies 64 BYTES. Size buffers as
// rows * 64 B (R6-R8 bug: K3 sized the weight buffer as rows * 32 B -> OOB).
__device__ __forceinline__ int swz(int row, int ch) {
    return row * 32 + (((ch ^ (row >> 1)) & 3) << 3);
}

// ---------------------------------------------------------------------------
// K1: z=0: x -> xt [B,HW,C] bf16; z=1: feat -> ft; z=2: weights ->
//   wdT2 [2s][9k][64oc][32c] bf16, woT2 [2s][9k][32oc][32c] bf16 (oc>=27 -> 0)
// ---------------------------------------------------------------------------
__global__ __launch_bounds__(256) void transpose_all(const float* __restrict__ x,
                                                     const float* __restrict__ feat,
                                                     const float* __restrict__ wdef,
                                                     const float* __restrict__ woff,
                                                     ushort* __restrict__ xt,
                                                     ushort* __restrict__ ft,
                                                     ushort* __restrict__ wdT2,
                                                     ushort* __restrict__ woT2) {
    int t = threadIdx.x;
    if (blockIdx.z == 2) {
        int id = (blockIdx.y * gridDim.x + blockIdx.x) * 256 + t;
        if (id < 36864) {  // [s][k][oc 64][c 32]
            int c2 = id & 31, oc = (id >> 5) & 63, ks = id >> 11;
            int k = ks % 9, s = ks / 9;
            wdT2[id] = f2bf(wdef[(oc * 64 + s * 32 + c2) * 9 + k]);
        } else if (id < 55296) {  // [s][k][oc 32][c 32]
            int i2 = id - 36864;
            int c2 = i2 & 31, oc = (i2 >> 5) & 31, ks = i2 >> 10;
            int k = ks % 9, s = ks / 9;
            woT2[i2] = (oc < 27) ? f2bf(woff[(oc * 64 + s * 32 + c2) * 9 + k]) : (ushort)0;
        }
        return;
    }
    __shared__ float tile[64][65];
    const float* src = blockIdx.z ? feat : x;
    ushort* dst0 = blockIdx.z ? ft : xt;
    int b = blockIdx.y, hw0 = blockIdx.x * 64;
    int lane = t & 63, grp = t >> 6;
    const float* xb = src + (size_t)b * Cn * HWn;
#pragma unroll
    for (int i = 0; i < 16; ++i) {
        int c = grp * 16 + i;
        tile[lane][c] = xb[(size_t)c * HWn + hw0 + lane];  // coalesced along hw
    }
    __syncthreads();
#pragma unroll
    for (int jj = 0; jj < 2; ++jj) {
        int px = jj * 32 + (t >> 3), ch = t & 7;
        s16x8 p;
#pragma unroll
        for (int j = 0; j < 8; ++j) p[j] = (short)f2bf(tile[px][ch * 8 + j]);
        *(s16x8*)(dst0 + ((size_t)(b * HWn + hw0 + px)) * Cn + ch * 8) = p;  // coalesced
    }
}

// ---------------------------------------------------------------------------
// K2: offset conv as windowed MFMA GEMM. Block = one row (128 px) x 32 oc.
// 4 waves x (32 px x 32 oc). 2 c-passes; 2 barriers/pass; no in-tap barriers.
// LDS audit: s_win 396 rows*64B = 25344 ok; s_wgt 288 rows*64B = 18432 ok.
// om planes: [B][27][H][W]; 0..8 off_x, 9..17 off_y, 18..26 mask (sigmoid).
// ---------------------------------------------------------------------------
__global__ __launch_bounds__(256, 3) void off_conv_kernel(const ushort* __restrict__ ft,
                                                          const ushort* __restrict__ woT2,
                                                          const float* __restrict__ b_off,
                                                          float* __restrict__ om) {
    __shared__ __align__(16) char smem[43776];
    ushort* s_win = (ushort*)smem;             // [3*132 rows] * 64 B = 25344 B
    ushort* s_wgt = (ushort*)(smem + 25344);   // [9*32 rows] * 64 B = 18432 B
    float* s_out = (float*)smem;               // [32][132] f32 overlay (16896 B)

    int t = threadIdx.x;
    int wv = t >> 6, l = t & 63;
    int q = l >> 4, r = l & 15;
    int h = blockIdx.x, b = blockIdx.y;
    const ushort* ft_b = ft + (size_t)b * HWn * Cn;

    f32x4 zero = {0.f, 0.f, 0.f, 0.f};
    s16x8 zz = {0, 0, 0, 0, 0, 0, 0, 0};
    f32x4 acc[2][2];
    acc[0][0] = zero; acc[0][1] = zero; acc[1][0] = zero; acc[1][1] = zero;

    for (int s = 0; s < 2; ++s) {
        // stage window: rows h-1..h+1 (clamped), cols -1..128 -> lin=row*132+col
        for (int j = t; j < 1560; j += 256) {
            int row = j / 520, rm = j - row * 520;
            int col = rm >> 2, ch = rm & 3;
            int rs = min(max(h - 1 + row, 0), Hn - 1);
            int cs = min(max(col - 1, 0), Wn - 1);
            s16x8 v = *(const s16x8*)(ft_b + (size_t)(rs * Wn + cs) * Cn + s * 32 + ch * 8);
            *(s16x8*)&s_win[swz(row * 132 + col, ch)] = v;
        }
        // stage weights half: [9][32][32]
        for (int j = t; j < 1152; j += 256) {
            int ro = j >> 2, ch = j & 3;
            s16x8 v = *(const s16x8*)(woT2 + (size_t)s * 9216 + ro * 32 + ch * 8);
            *(s16x8*)&s_wgt[swz(ro, ch)] = v;
        }
        __syncthreads();
#pragma unroll 3
        for (int k = 0; k < 9; ++k) {
            int dy = k / 3 - 1, dx = k % 3 - 1;
            int y = h + dy;
            bool yv = (y >= 0) && (y < Hn);
#pragma unroll
            for (int mt = 0; mt < 2; ++mt) {
                int px = wv * 32 + mt * 16 + r;
                int xx = px + dx;
                bool valid = yv && (xx >= 0) && (xx < Wn);
                int lin = (dy + 1) * 132 + px + dx + 1;
                s16x8 av = *(const s16x8*)&s_win[swz(lin, q)];
                av = valid ? av : zz;
#pragma unroll
                for (int ot = 0; ot < 2; ++ot) {
                    s16x8 bv = *(const s16x8*)&s_wgt[swz(k * 32 + ot * 16 + r, q)];
                    acc[mt][ot] = __builtin_amdgcn_mfma_f32_16x16x32_bf16(av, bv, acc[mt][ot], 0, 0, 0);
                }
            }
        }
        __syncthreads();
    }
    // epilogue: bias + sigmoid(mask), stage [oc][px], coalesced plane store
#pragma unroll
    for (int mt = 0; mt < 2; ++mt)
#pragma unroll
        for (int ot = 0; ot < 2; ++ot) {
            int oc = ot * 16 + r;
            float bo = (oc < 27) ? b_off[oc] : 0.f;
#pragma unroll
            for (int reg = 0; reg < 4; ++reg) {
                int px = wv * 32 + mt * 16 + q * 4 + reg;
                float v = acc[mt][ot][reg] + bo;
                if (oc >= 18 && oc < 27) v = 1.f / (1.f + __expf(-v));
                s_out[oc * 132 + px] = v;
            }
        }
    __syncthreads();
    for (int idx = t; idx < 27 * 128; idx += 256) {
        int o = idx >> 7, px = idx & 127;
        om[((size_t)b * 27 + o) * HWn + h * Wn + px] = s_out[o * 132 + px];
    }
}

// ---------------------------------------------------------------------------
// K3: mega = sampling + main GEMM. Block = 64 px x 64 oc, 4 waves x 16 px.
// 2 c-passes; per pass: stage window half (340 rows = 21760 B) once, stage
// weights in TWO tap-groups (taps 0-4: 320 rows = 20480 B; taps 5-8: 256
// rows) into one 20480-B buffer. LDS total 42256 B -> 3 blocks/CU (real).
// R6-R8 BUG (fixed): weight buffer was sized 18432 B for 36864 B of rows
// (rows are 64 B, not 32 B) -> OOB LDS writes past the block allocation.
// s_om overlays the weight buffer (om consumed into registers before any
// weight staging). Offsets live in registers (omv[27]).
// ---------------------------------------------------------------------------
__global__ __launch_bounds__(256, 3) void mega_kernel(const ushort* __restrict__ xt,
                                                      const ushort* __restrict__ wdT2,
                                                      const float* __restrict__ om,
                                                      const float* __restrict__ b_def,
                                                      float* __restrict__ out) {
    __shared__ __align__(16) char smem[42272];
    ushort* s_win = (ushort*)smem;               // 340 rows * 64 B = 21760 B
    ushort* s_wgt = (ushort*)(smem + 21760);     // 320 rows * 64 B = 20480 B
    int* s_flag = (int*)(smem + 42240);          // 16 B
    float* s_om = (float*)(smem + 21760);        // [27][68] f32 = 7344 B overlay in wgt
    float* s_out = (float*)smem;                 // [64][68] f32 = 17408 B overlay in win

    int t = threadIdx.x;
    int wv = t >> 6, l = t & 63;
    int q = l >> 4, r = l & 15;
    int p0 = blockIdx.x * 64;
    int b = p0 >> 14;
    int rem = p0 & (HWn - 1);
    int h = rem >> 7;
    int wbase = rem & (Wn - 1);
    int pxi = wv * 16 + r;
    float pxif = (float)pxi;
    const ushort* xt_b = xt + (size_t)b * HWn * Cn;

    // ---- stage om (27 planes x 64 px), load per-lane offsets to registers ----
    for (int j = t; j < 1728; j += 256) {
        int o = j >> 6, px = j & 63;
        s_om[o * 68 + px] = om[((size_t)b * 27 + o) * HWn + h * Wn + wbase + px];
    }
    __syncthreads();
    float omv[27];
#pragma unroll
    for (int o = 0; o < 27; ++o) omv[o] = s_om[o * 68 + pxi];
    // fast/slow vote: all 9 taps' samples inside the 5x68 window
    bool okp = true;
#pragma unroll
    for (int k = 0; k < 9; ++k) {
        float uy = (float)(k / 3 - 1) + omv[9 + k];
        float ux = pxif + (float)(k % 3 - 1) + omv[k];
        okp = okp && (uy >= -2.f) && (uy < 2.f) && (ux >= -2.f) && (ux < 65.f);
    }
    int allok = __all(okp) ? 1 : 0;   // full wave active (R6 bug #1)
    if (l == 0) s_flag[wv] = allok;
    __syncthreads();  // flag visible; om reads done (wgt staging may overwrite)
    int fast = s_flag[0] & s_flag[1] & s_flag[2] & s_flag[3];

    f32x4 zero = {0.f, 0.f, 0.f, 0.f};
    f32x4 acc[4];
    acc[0] = zero; acc[1] = zero; acc[2] = zero; acc[3] = zero;

    if (fast) {
        // one tap: bilinear from LDS window -> A-frag -> 4 MFMAs vs staged wgt
        auto tap = [&](int k, int krel) {
            float uy = (float)(k / 3 - 1) + omv[9 + k];
            float ux = pxif + (float)(k % 3 - 1) + omv[k];
            float mv = omv[18 + k];
            float y0f = floorf(uy), x0f = floorf(ux);
            float fy = uy - y0f, fx = ux - x0f;
            int iy = (int)y0f + 2;  // 0..3
            int ix = (int)x0f + 2;  // 0..66
            int yab = h + (int)y0f, xab = wbase + (int)x0f;
            bool vy0 = (yab >= 0) && (yab < Hn);
            bool vy1 = (yab + 1 >= 0) && (yab + 1 < Hn);
            bool vx0 = (xab >= 0) && (xab < Wn);
            bool vx1 = (xab + 1 >= 0) && (xab + 1 < Wn);
            float g0 = (vy0 && vx0) ? (1.f - fy) * (1.f - fx) * mv : 0.f;
            float g1 = (vy0 && vx1) ? (1.f - fy) * fx * mv : 0.f;
            float g2 = (vy1 && vx0) ? fy * (1.f - fx) * mv : 0.f;
            float g3 = (vy1 && vx1) ? fy * fx * mv : 0.f;
            int lin0 = iy * 68 + ix;
            s16x8 q0 = *(const s16x8*)&s_win[swz(lin0, q)];
            s16x8 q1 = *(const s16x8*)&s_win[swz(lin0 + 1, q)];
            s16x8 q2 = *(const s16x8*)&s_win[swz(lin0 + 68, q)];
            s16x8 q3 = *(const s16x8*)&s_win[swz(lin0 + 69, q)];
            s16x8 af;
#pragma unroll
            for (int j = 0; j < 8; ++j) {
                float rr = g0 * bf2f((unsigned short)q0[j]) + g1 * bf2f((unsigned short)q1[j])
                         + g2 * bf2f((unsigned short)q2[j]) + g3 * bf2f((unsigned short)q3[j]);
                af[j] = (short)f2bf(rr);
            }
#pragma unroll
            for (int ot = 0; ot < 4; ++ot) {
                s16x8 bv = *(const s16x8*)&s_wgt[swz(krel * 64 + ot * 16 + r, q)];
                acc[ot] = __builtin_amdgcn_mfma_f32_16x16x32_bf16(af, bv, acc[ot], 0, 0, 0);
            }
        };

        for (int s = 0; s < 2; ++s) {
            // stage x window rows h-2..h+2, cols wbase-2..wbase+65 (clamped)
            for (int j = t; j < 1360; j += 256) {
                int row = j / 272, rm = j - row * 272;
                int col = rm >> 2, ch = rm & 3;
                int rs = min(max(h - 2 + row, 0), Hn - 1);
                int cs = min(max(wbase - 2 + col, 0), Wn - 1);
                s16x8 v = *(const s16x8*)(xt_b + (size_t)(rs * Wn + cs) * Cn + s * 32 + ch * 8);
                *(s16x8*)&s_win[swz(row * 68 + col, ch)] = v;
            }
            // group A weights: taps 0..4 (rows 0..319 of this c-half)
            for (int j = t; j < 1280; j += 256) {
                int ro = j >> 2, ch = j & 3;
                s16x8 v = *(const s16x8*)(wdT2 + (size_t)s * 18432 + ro * 32 + ch * 8);
                *(s16x8*)&s_wgt[swz(ro, ch)] = v;
            }
            __syncthreads();
#pragma unroll 5
            for (int k = 0; k < 5; ++k) tap(k, k);
            __syncthreads();  // group-A weight reads done
            // group B weights: taps 5..8 (rows 320..575 -> buffer rows 0..255)
            for (int j = t; j < 1024; j += 256) {
                int ro = j >> 2, ch = j & 3;
                s16x8 v = *(const s16x8*)(wdT2 + (size_t)s * 18432 + (320 + ro) * 32 + ch * 8);
                *(s16x8*)&s_wgt[swz(ro, ch)] = v;
            }
            __syncthreads();
#pragma unroll 4
            for (int k = 5; k < 9; ++k) tap(k, k - 5);
            __syncthreads();  // pass reads done; next pass restages win/wgt
        }
    } else {
        // slow path (rare, any-input correct): global gathers + global weights
#pragma unroll 1
        for (int k = 0; k < 9; ++k) {
            float ys = (float)(h + k / 3 - 1) + omv[9 + k];
            float xs = (float)(wbase + pxi + k % 3 - 1) + omv[k];
            float mv = omv[18 + k];
            float y0f = floorf(ys), x0f = floorf(xs);
            float fy = ys - y0f, fx = xs - x0f;
            int y0 = (int)y0f, x0 = (int)x0f;
            float g[4];
            int a[4];
#pragma unroll
            for (int n = 0; n < 4; ++n) {
                int yy = y0 + (n >> 1), xx = x0 + (n & 1);
                bool valid = (yy >= 0) && (yy < Hn) && (xx >= 0) && (xx < Wn);
                float wgt = ((n >> 1) ? fy : 1.f - fy) * ((n & 1) ? fx : 1.f - fx) * mv;
                g[n] = valid ? wgt : 0.f;
                int yc = min(max(yy, 0), Hn - 1), xc = min(max(xx, 0), Wn - 1);
                a[n] = (yc * Wn + xc) * Cn;
            }
#pragma unroll
            for (int s = 0; s < 2; ++s) {
                int c = s * 32 + q * 8;
                s16x8 q0 = *(const s16x8*)(xt_b + a[0] + c);
                s16x8 q1 = *(const s16x8*)(xt_b + a[1] + c);
                s16x8 q2 = *(const s16x8*)(xt_b + a[2] + c);
                s16x8 q3 = *(const s16x8*)(xt_b + a[3] + c);
                s16x8 af;
#pragma unroll
                for (int j = 0; j < 8; ++j) {
                    float rr = g[0] * bf2f((unsigned short)q0[j]) + g[1] * bf2f((unsigned short)q1[j])
                             + g[2] * bf2f((unsigned short)q2[j]) + g[3] * bf2f((unsigned short)q3[j]);
                    af[j] = (short)f2bf(rr);
                }
#pragma unroll
                for (int ot = 0; ot < 4; ++ot) {
                    s16x8 bv = *(const s16x8*)(wdT2 + (size_t)s * 18432
                                               + (size_t)(k * 64 + ot * 16 + r) * 32 + q * 8);
                    acc[ot] = __builtin_amdgcn_mfma_f32_16x16x32_bf16(af, bv, acc[ot], 0, 0, 0);
                }
            }
        }
    }
    __syncthreads();  // join: all LDS reads done; smem becomes s_out

    // ---- epilogue: bias + ReLU, stage [oc][px], coalesced store ----
#pragma unroll
    for (int ot = 0; ot < 4; ++ot) {
        int oc = ot * 16 + r;
        float bv = b_def[oc];
        f32x4 vv;
#pragma unroll
        for (int reg = 0; reg < 4; ++reg) vv[reg] = fmaxf(acc[ot][reg] + bv, 0.f);
        *(f32x4*)&s_out[oc * 68 + wv * 16 + q * 4] = vv;
    }
    __syncthreads();
    {
        int px = t & 63, og = t >> 6;
        float* ob = out + ((size_t)b * On) * HWn + h * Wn + wbase;
#pragma unroll
        for (int j = 0; j < 16; ++j) {
            int oc = og * 16 + j;
            ob[(size_t)oc * HWn + px] = s_out[oc * 68 + px];
        }
    }
}

// ---------------------------------------------------------------------------
extern "C" void kernel_launch(void* const* d_in, const int* in_sizes, int n_in,
                              void* d_out, int out_size, void* d_ws, size_t ws_size,
                              hipStream_t stream) {
    const float* x = (const float*)d_in[0];
    const float* feat = (const float*)d_in[1];
    const float* w_off = (const float*)d_in[2];
    const float* b_off = (const float*)d_in[3];
    const float* w_def = (const float*)d_in[4];
    const float* b_def = (const float*)d_in[5];
    float* out = (float*)d_out;

    char* ws = (char*)d_ws;
    ushort* xt = (ushort*)ws;                           // 8 MB [B,HW,C] bf16
    ushort* ft = (ushort*)(ws + 8388608);               // 8 MB [B,HW,C] bf16
    ushort* wdT2 = (ushort*)(ws + 16777216);            // 73728 B [2][9][64][32]
    ushort* woT2 = (ushort*)(ws + 16850944);            // 36864 B [2][9][32][32]
    float* om = (float*)(ws + 16887808);                // 6.75 MB [B][27][H][W]

    hipLaunchKernelGGL(transpose_all, dim3(HWn / 64, Bn, 3), dim3(256), 0, stream,
                       x, feat, w_def, w_off, xt, ft, wdT2, woT2);
    hipLaunchKernelGGL(off_conv_kernel, dim3(Hn, Bn), dim3(256), 0, stream,
                       ft, woT2, b_off, om);
    hipLaunchKernelGGL(mega_kernel, dim3((Bn * HWn) / 64), dim3(256), 0, stream,
                       xt, wdT2, om, b_def, out);
}

// Round 10
// 140.269 us; speedup vs baseline: 1.0548x; 1.0548x over previous
//
#include <hip/hip_runtime.h>
#include <math.h>

#define Bn 4
#define Cn 64
#define On 64
#define Hn 128
#define Wn 128
#define HWn (Hn * Wn)

typedef __attribute__((ext_vector_type(8))) short s16x8;
typedef __attribute__((ext_vector_type(4))) float f32x4;

__device__ __forceinline__ unsigned short f2bf(float f) {
    unsigned u = __float_as_uint(f);
    u += 0x7fffu + ((u >> 16) & 1u);  // RTNE (finite values)
    return (unsigned short)(u >> 16);
}
__device__ __forceinline__ float bf2f(unsigned short u) {
    return __uint_as_float(((unsigned)u) << 16);
}
// K2 swizzle: 64-B LDS rows (32 ushorts), chunk swizzle -> 2-way (free) banks
__device__ __forceinline__ int swz(int row, int ch) {
    return row * 32 + (((ch ^ (row >> 1)) & 3) << 3);
}

// ---------------------------------------------------------------------------
// K1: z=0: x -> xt [B,HW,C] bf16; z=1: feat -> ft; z=2: weights ->
//   wdT2 [2s][9k][64oc][32c] bf16, woT2 [2s][9k][32oc][32c] bf16 (oc>=27 -> 0)
// ---------------------------------------------------------------------------
__global__ __launch_bounds__(256) void transpose_all(const float* __restrict__ x,
                                                     const float* __restrict__ feat,
                                                     const float* __restrict__ wdef,
                                                     const float* __restrict__ woff,
                                                     ushort* __restrict__ xt,
                                                     ushort* __restrict__ ft,
                                                     ushort* __restrict__ wdT2,
                                                     ushort* __restrict__ woT2) {
    int t = threadIdx.x;
    if (blockIdx.z == 2) {
        int id = (blockIdx.y * gridDim.x + blockIdx.x) * 256 + t;
        if (id < 36864) {  // [s][k][oc 64][c 32]
            int c2 = id & 31, oc = (id >> 5) & 63, ks = id >> 11;
            int k = ks % 9, s = ks / 9;
            wdT2[id] = f2bf(wdef[(oc * 64 + s * 32 + c2) * 9 + k]);
        } else if (id < 55296) {  // [s][k][oc 32][c 32]
            int i2 = id - 36864;
            int c2 = i2 & 31, oc = (i2 >> 5) & 31, ks = i2 >> 10;
            int k = ks % 9, s = ks / 9;
            woT2[i2] = (oc < 27) ? f2bf(woff[(oc * 64 + s * 32 + c2) * 9 + k]) : (ushort)0;
        }
        return;
    }
    __shared__ float tile[64][65];
    const float* src = blockIdx.z ? feat : x;
    ushort* dst0 = blockIdx.z ? ft : xt;
    int b = blockIdx.y, hw0 = blockIdx.x * 64;
    int lane = t & 63, grp = t >> 6;
    const float* xb = src + (size_t)b * Cn * HWn;
#pragma unroll
    for (int i = 0; i < 16; ++i) {
        int c = grp * 16 + i;
        tile[lane][c] = xb[(size_t)c * HWn + hw0 + lane];  // coalesced along hw
    }
    __syncthreads();
#pragma unroll
    for (int jj = 0; jj < 2; ++jj) {
        int px = jj * 32 + (t >> 3), ch = t & 7;
        s16x8 p;
#pragma unroll
        for (int j = 0; j < 8; ++j) p[j] = (short)f2bf(tile[px][ch * 8 + j]);
        *(s16x8*)(dst0 + ((size_t)(b * HWn + hw0 + px)) * Cn + ch * 8) = p;  // coalesced
    }
}

// ---------------------------------------------------------------------------
// K2: offset conv as windowed MFMA GEMM (unchanged from R9 — passes).
// ---------------------------------------------------------------------------
__global__ __launch_bounds__(256, 3) void off_conv_kernel(const ushort* __restrict__ ft,
                                                          const ushort* __restrict__ woT2,
                                                          const float* __restrict__ b_off,
                                                          float* __restrict__ om) {
    __shared__ __align__(16) char smem[43776];
    ushort* s_win = (ushort*)smem;             // [3*132 rows] * 64 B = 25344 B
    ushort* s_wgt = (ushort*)(smem + 25344);   // [9*32 rows] * 64 B = 18432 B
    float* s_out = (float*)smem;               // [32][132] f32 overlay (16896 B)

    int t = threadIdx.x;
    int wv = t >> 6, l = t & 63;
    int q = l >> 4, r = l & 15;
    int h = blockIdx.x, b = blockIdx.y;
    const ushort* ft_b = ft + (size_t)b * HWn * Cn;

    f32x4 zero = {0.f, 0.f, 0.f, 0.f};
    s16x8 zz = {0, 0, 0, 0, 0, 0, 0, 0};
    f32x4 acc[2][2];
    acc[0][0] = zero; acc[0][1] = zero; acc[1][0] = zero; acc[1][1] = zero;

    for (int s = 0; s < 2; ++s) {
        for (int j = t; j < 1560; j += 256) {
            int row = j / 520, rm = j - row * 520;
            int col = rm >> 2, ch = rm & 3;
            int rs = min(max(h - 1 + row, 0), Hn - 1);
            int cs = min(max(col - 1, 0), Wn - 1);
            s16x8 v = *(const s16x8*)(ft_b + (size_t)(rs * Wn + cs) * Cn + s * 32 + ch * 8);
            *(s16x8*)&s_win[swz(row * 132 + col, ch)] = v;
        }
        for (int j = t; j < 1152; j += 256) {
            int ro = j >> 2, ch = j & 3;
            s16x8 v = *(const s16x8*)(woT2 + (size_t)s * 9216 + ro * 32 + ch * 8);
            *(s16x8*)&s_wgt[swz(ro, ch)] = v;
        }
        __syncthreads();
#pragma unroll 3
        for (int k = 0; k < 9; ++k) {
            int dy = k / 3 - 1, dx = k % 3 - 1;
            int y = h + dy;
            bool yv = (y >= 0) && (y < Hn);
#pragma unroll
            for (int mt = 0; mt < 2; ++mt) {
                int px = wv * 32 + mt * 16 + r;
                int xx = px + dx;
                bool valid = yv && (xx >= 0) && (xx < Wn);
                int lin = (dy + 1) * 132 + px + dx + 1;
                s16x8 av = *(const s16x8*)&s_win[swz(lin, q)];
                av = valid ? av : zz;
#pragma unroll
                for (int ot = 0; ot < 2; ++ot) {
                    s16x8 bv = *(const s16x8*)&s_wgt[swz(k * 32 + ot * 16 + r, q)];
                    acc[mt][ot] = __builtin_amdgcn_mfma_f32_16x16x32_bf16(av, bv, acc[mt][ot], 0, 0, 0);
                }
            }
        }
        __syncthreads();
    }
#pragma unroll
    for (int mt = 0; mt < 2; ++mt)
#pragma unroll
        for (int ot = 0; ot < 2; ++ot) {
            int oc = ot * 16 + r;
            float bo = (oc < 27) ? b_off[oc] : 0.f;
#pragma unroll
            for (int reg = 0; reg < 4; ++reg) {
                int px = wv * 32 + mt * 16 + q * 4 + reg;
                float v = acc[mt][ot][reg] + bo;
                if (oc >= 18 && oc < 27) v = 1.f / (1.f + __expf(-v));
                s_out[oc * 132 + px] = v;
            }
        }
    __syncthreads();
    for (int idx = t; idx < 27 * 128; idx += 256) {
        int o = idx >> 7, px = idx & 127;
        om[((size_t)b * 27 + o) * HWn + h * Wn + px] = s_out[o * 132 + px];
    }
}

// ---------------------------------------------------------------------------
// K3: mega. Block = 64 px x 64 oc, 4 waves x 16 px.
// R10 changes vs R9:
//  (1) XCD swizzle: blk = (bx&7)*128 + (bx>>3) -> each XCD gets a contiguous
//      8192-px band; its 5-row xt windows (~2.2 MB) fit the private 4 MB L2.
//  (2) SINGLE c-pass: full-64ch window, 340 lins x 128 B = 43520 B, staged
//      once. Chunk rotation slot=(cidx+lin)&7 -> staging writes and gather
//      reads both hit the 8-cyc/KB LDS minimum (conflict-free).
//  (3) Weights per-tap from global wdT2 (L2-resident 72 KB) — no wgt LDS.
// Barriers: om-stage, vote/om-consumed, window-stage, pre-epilogue (+1 in
// epilogue). Overlays: s_om (6912 B) and s_out (17408 B) inside s_win.
// ---------------------------------------------------------------------------
__global__ __launch_bounds__(256, 3) void mega_kernel(const ushort* __restrict__ xt,
                                                      const ushort* __restrict__ wdT2,
                                                      const float* __restrict__ om,
                                                      const float* __restrict__ b_def,
                                                      float* __restrict__ out) {
    __shared__ __align__(16) char smem[43536];
    ushort* s_win = (ushort*)smem;            // 340 lins * 128 B = 43520 B
    int* s_flag = (int*)(smem + 43520);       // 16 B
    float* s_om = (float*)smem;               // [27][64] f32 = 6912 B overlay
    float* s_out = (float*)smem;              // [64][68] f32 = 17408 B overlay

    int t = threadIdx.x;
    int wv = t >> 6, l = t & 63;
    int q = l >> 4, r = l & 15;
    int blk = (blockIdx.x & 7) * 128 + (blockIdx.x >> 3);  // XCD band swizzle
    int p0 = blk * 64;
    int b = p0 >> 14;
    int rem = p0 & (HWn - 1);
    int h = rem >> 7;
    int wbase = rem & (Wn - 1);
    int pxi = wv * 16 + r;
    float pxif = (float)pxi;
    const ushort* xt_b = xt + (size_t)b * HWn * Cn;

    // ---- stage om (27 planes x 64 px) -> registers ----
    for (int j = t; j < 1728; j += 256) {
        int o = j >> 6, px = j & 63;
        s_om[o * 64 + px] = om[((size_t)b * 27 + o) * HWn + h * Wn + wbase + px];
    }
    __syncthreads();
    float omv[27];
#pragma unroll
    for (int o = 0; o < 27; ++o) omv[o] = s_om[o * 64 + pxi];
    // fast/slow vote: all 9 taps' samples inside the 5x68 window
    bool okp = true;
#pragma unroll
    for (int k = 0; k < 9; ++k) {
        float uy = (float)(k / 3 - 1) + omv[9 + k];
        float ux = pxif + (float)(k % 3 - 1) + omv[k];
        okp = okp && (uy >= -2.f) && (uy < 2.f) && (ux >= -2.f) && (ux < 65.f);
    }
    int allok = __all(okp) ? 1 : 0;  // full wave active (R6 bug #1)
    if (l == 0) s_flag[wv] = allok;
    __syncthreads();  // flags visible; all om reads done (staging overwrites)
    int fast = s_flag[0] & s_flag[1] & s_flag[2] & s_flag[3];

    // ---- stage x window: rows h-2..h+2, cols wbase-2..wbase+65 (clamped),
    //      full 64 ch; chunk cidx stored at slot (cidx+lin)&7 ----
    for (int j = t; j < 2720; j += 256) {
        int lin = j >> 3, cidx = j & 7;
        int row = lin / 68, col = lin - row * 68;
        int rs = min(max(h - 2 + row, 0), Hn - 1);
        int cs = min(max(wbase - 2 + col, 0), Wn - 1);
        s16x8 v = *(const s16x8*)(xt_b + (size_t)(rs * Wn + cs) * Cn + cidx * 8);
        *(s16x8*)&s_win[lin * 64 + (((cidx + lin) & 7) << 3)] = v;
    }
    __syncthreads();

    f32x4 zero = {0.f, 0.f, 0.f, 0.f};
    f32x4 acc[4];
    acc[0] = zero; acc[1] = zero; acc[2] = zero; acc[3] = zero;

    if (fast) {
#pragma unroll 3
        for (int k = 0; k < 9; ++k) {
            float uy = (float)(k / 3 - 1) + omv[9 + k];
            float ux = pxif + (float)(k % 3 - 1) + omv[k];
            float mv = omv[18 + k];
            float y0f = floorf(uy), x0f = floorf(ux);
            float fy = uy - y0f, fx = ux - x0f;
            int iy = (int)y0f + 2;  // 0..3
            int ix = (int)x0f + 2;  // 0..66
            int yab = h + (int)y0f, xab = wbase + (int)x0f;
            bool vy0 = (yab >= 0) && (yab < Hn);
            bool vy1 = (yab + 1 >= 0) && (yab + 1 < Hn);
            bool vx0 = (xab >= 0) && (xab < Wn);
            bool vx1 = (xab + 1 >= 0) && (xab + 1 < Wn);
            float g0 = (vy0 && vx0) ? (1.f - fy) * (1.f - fx) * mv : 0.f;
            float g1 = (vy0 && vx1) ? (1.f - fy) * fx * mv : 0.f;
            float g2 = (vy1 && vx0) ? fy * (1.f - fx) * mv : 0.f;
            float g3 = (vy1 && vx1) ? fy * fx * mv : 0.f;
            int l0 = iy * 68 + ix, l1 = l0 + 1, l2 = l0 + 68, l3 = l0 + 69;
            // weights for this tap (global, L2-hot): 8 x b128
            s16x8 bw[2][4];
#pragma unroll
            for (int s = 0; s < 2; ++s)
#pragma unroll
                for (int ot = 0; ot < 4; ++ot)
                    bw[s][ot] = *(const s16x8*)(wdT2 + (size_t)s * 18432
                                                + (size_t)(k * 64 + ot * 16 + r) * 32 + q * 8);
            s16x8 af[2];
#pragma unroll
            for (int s = 0; s < 2; ++s) {
                int c = s * 4 + q;  // logical chunk
                s16x8 q0 = *(const s16x8*)&s_win[l0 * 64 + (((c + l0) & 7) << 3)];
                s16x8 q1 = *(const s16x8*)&s_win[l1 * 64 + (((c + l1) & 7) << 3)];
                s16x8 q2 = *(const s16x8*)&s_win[l2 * 64 + (((c + l2) & 7) << 3)];
                s16x8 q3 = *(const s16x8*)&s_win[l3 * 64 + (((c + l3) & 7) << 3)];
                s16x8 p;
#pragma unroll
                for (int j = 0; j < 8; ++j) {
                    float rr = g0 * bf2f((unsigned short)q0[j]) + g1 * bf2f((unsigned short)q1[j])
                             + g2 * bf2f((unsigned short)q2[j]) + g3 * bf2f((unsigned short)q3[j]);
                    p[j] = (short)f2bf(rr);
                }
                af[s] = p;
            }
#pragma unroll
            for (int s = 0; s < 2; ++s)
#pragma unroll
                for (int ot = 0; ot < 4; ++ot)
                    acc[ot] = __builtin_amdgcn_mfma_f32_16x16x32_bf16(af[s], bw[s][ot], acc[ot], 0, 0, 0);
        }
    } else {
        // slow path (rare, any-input correct): global gathers + global weights
#pragma unroll 1
        for (int k = 0; k < 9; ++k) {
            float ys = (float)(h + k / 3 - 1) + omv[9 + k];
            float xs = (float)(wbase + pxi + k % 3 - 1) + omv[k];
            float mv = omv[18 + k];
            float y0f = floorf(ys), x0f = floorf(xs);
            float fy = ys - y0f, fx = xs - x0f;
            int y0 = (int)y0f, x0 = (int)x0f;
            float g[4];
            int a[4];
#pragma unroll
            for (int n = 0; n < 4; ++n) {
                int yy = y0 + (n >> 1), xx = x0 + (n & 1);
                bool valid = (yy >= 0) && (yy < Hn) && (xx >= 0) && (xx < Wn);
                float wgt = ((n >> 1) ? fy : 1.f - fy) * ((n & 1) ? fx : 1.f - fx) * mv;
                g[n] = valid ? wgt : 0.f;
                int yc = min(max(yy, 0), Hn - 1), xc = min(max(xx, 0), Wn - 1);
                a[n] = (yc * Wn + xc) * Cn;
            }
#pragma unroll
            for (int s = 0; s < 2; ++s) {
                int c = s * 32 + q * 8;
                s16x8 q0 = *(const s16x8*)(xt_b + a[0] + c);
                s16x8 q1 = *(const s16x8*)(xt_b + a[1] + c);
                s16x8 q2 = *(const s16x8*)(xt_b + a[2] + c);
                s16x8 q3 = *(const s16x8*)(xt_b + a[3] + c);
                s16x8 af;
#pragma unroll
                for (int j = 0; j < 8; ++j) {
                    float rr = g[0] * bf2f((unsigned short)q0[j]) + g[1] * bf2f((unsigned short)q1[j])
                             + g[2] * bf2f((unsigned short)q2[j]) + g[3] * bf2f((unsigned short)q3[j]);
                    af[j] = (short)f2bf(rr);
                }
#pragma unroll
                for (int ot = 0; ot < 4; ++ot) {
                    s16x8 bv = *(const s16x8*)(wdT2 + (size_t)s * 18432
                                               + (size_t)(k * 64 + ot * 16 + r) * 32 + q * 8);
                    acc[ot] = __builtin_amdgcn_mfma_f32_16x16x32_bf16(af, bv, acc[ot], 0, 0, 0);
                }
            }
        }
    }
    __syncthreads();  // all window reads done; smem becomes s_out

    // ---- epilogue: bias + ReLU, stage [oc][px], coalesced store ----
#pragma unroll
    for (int ot = 0; ot < 4; ++ot) {
        int oc = ot * 16 + r;
        float bv = b_def[oc];
        f32x4 vv;
#pragma unroll
        for (int reg = 0; reg < 4; ++reg) vv[reg] = fmaxf(acc[ot][reg] + bv, 0.f);
        *(f32x4*)&s_out[oc * 68 + wv * 16 + q * 4] = vv;
    }
    __syncthreads();
    {
        int px = t & 63, og = t >> 6;
        float* ob = out + ((size_t)b * On) * HWn + h * Wn + wbase;
#pragma unroll
        for (int j = 0; j < 16; ++j) {
            int oc = og * 16 + j;
            ob[(size_t)oc * HWn + px] = s_out[oc * 68 + px];
        }
    }
}

// ---------------------------------------------------------------------------
extern "C" void kernel_launch(void* const* d_in, const int* in_sizes, int n_in,
                              void* d_out, int out_size, void* d_ws, size_t ws_size,
                              hipStream_t stream) {
    const float* x = (const float*)d_in[0];
    const float* feat = (const float*)d_in[1];
    const float* w_off = (const float*)d_in[2];
    const float* b_off = (const float*)d_in[3];
    const float* w_def = (const float*)d_in[4];
    const float* b_def = (const float*)d_in[5];
    float* out = (float*)d_out;

    char* ws = (char*)d_ws;
    ushort* xt = (ushort*)ws;                           // 8 MB [B,HW,C] bf16
    ushort* ft = (ushort*)(ws + 8388608);               // 8 MB [B,HW,C] bf16
    ushort* wdT2 = (ushort*)(ws + 16777216);            // 73728 B [2][9][64][32]
    ushort* woT2 = (ushort*)(ws + 16850944);            // 36864 B [2][9][32][32]
    float* om = (float*)(ws + 16887808);                // 6.75 MB [B][27][H][W]

    hipLaunchKernelGGL(transpose_all, dim3(HWn / 64, Bn, 3), dim3(256), 0, stream,
                       x, feat, w_def, w_off, xt, ft, wdT2, woT2);
    hipLaunchKernelGGL(off_conv_kernel, dim3(Hn, Bn), dim3(256), 0, stream,
                       ft, woT2, b_off, om);
    hipLaunchKernelGGL(mega_kernel, dim3((Bn * HWn) / 64), dim3(256), 0, stream,
                       xt, wdT2, om, b_def, out);
}